// Round 1
// baseline (687.375 us; speedup 1.0000x reference)
//
#include <hip/hip_runtime.h>
#include <hip/hip_bf16.h>
#include <stdint.h>

// GCN 4-layer: h = relu(D^-1/2 (A+I) D^-1/2 (x W) + b) x3, final layer no relu.
// Strategy: fold dinv into GEMM output (h' = xW * dinv[row]); build CSR-ish
// edge partition per call (deterministic set per node, order irrelevant for sum
// up to f32 rounding); aggregation = gather + sum, wave-per-node.

#define TPB 256

__global__ __launch_bounds__(TPB) void k_deg(const int* __restrict__ dst,
                                             unsigned int* __restrict__ deg, int E) {
    int e = blockIdx.x * TPB + threadIdx.x;
    if (e < E) atomicAdd(&deg[dst[e]], 1u);
}

__global__ __launch_bounds__(TPB) void k_dinv_start(const unsigned int* __restrict__ deg,
                                                    float* __restrict__ dinv,
                                                    int* __restrict__ start,
                                                    unsigned int* __restrict__ gcounter,
                                                    int n) {
    int i = blockIdx.x * TPB + threadIdx.x;
    int lane = threadIdx.x & 63;
    int d = 0;
    if (i < n) {
        unsigned int dg = deg[i];
        d = (int)dg;
        dinv[i] = rsqrtf((float)(dg + 1u));   // +1 self loop; always > 0
    }
    // wave-inclusive scan of d
    int v = d;
#pragma unroll
    for (int off = 1; off < 64; off <<= 1) {
        int u = __shfl_up(v, off, 64);
        if (lane >= off) v += u;
    }
    int total = __shfl(v, 63, 64);
    int base = 0;
    if (lane == 0) base = (int)atomicAdd(gcounter, (unsigned int)total);
    base = __shfl(base, 0, 64);
    if (i < n) start[i] = base + v - d;       // exclusive within wave + global base
}

__global__ __launch_bounds__(TPB) void k_scatter(const int* __restrict__ src,
                                                 const int* __restrict__ dst,
                                                 const int* __restrict__ start,
                                                 unsigned int* __restrict__ cursor,
                                                 int* __restrict__ ebuf, int E) {
    int e = blockIdx.x * TPB + threadIdx.x;
    if (e < E) {
        int d = dst[e];
        unsigned int p = atomicAdd(&cursor[d], 1u);
        ebuf[start[d] + (int)p] = src[e];
    }
}

// H[row, :] = (X[row, :] @ W) * dinv[row]
template <int K, int F>
__global__ __launch_bounds__(TPB) void k_gemm(const float* __restrict__ X,
                                              const float* __restrict__ W,
                                              const float* __restrict__ dinv,
                                              float* __restrict__ H, int n) {
    __shared__ float Wl[K * F];
    for (int i = threadIdx.x; i < K * F; i += TPB) Wl[i] = W[i];
    __syncthreads();
    int row = blockIdx.x * TPB + threadIdx.x;
    if (row >= n) return;
    float acc[F];
#pragma unroll
    for (int j = 0; j < F; ++j) acc[j] = 0.f;
    const float* xr = X + (size_t)row * K;
#pragma unroll 1
    for (int k = 0; k < K; k += 4) {
        float4 xv = *reinterpret_cast<const float4*>(xr + k);
        float xs[4] = {xv.x, xv.y, xv.z, xv.w};
#pragma unroll
        for (int kk = 0; kk < 4; ++kk) {
            float xk = xs[kk];
#pragma unroll
            for (int j = 0; j < F; ++j)
                acc[j] = fmaf(xk, Wl[(k + kk) * F + j], acc[j]);
        }
    }
    float di = dinv[row];
    float* hr = H + (size_t)row * F;
#pragma unroll
    for (int j = 0; j < F; j += 4) {
        float4 o;
        o.x = acc[j] * di; o.y = acc[j + 1] * di;
        o.z = acc[j + 2] * di; o.w = acc[j + 3] * di;
        *reinterpret_cast<float4*>(hr + j) = o;
    }
}

// Out[node, lane] = act(dinv[node] * (H[node,lane] + sum_{e in-edges} H[src,lane]) + b[lane])
template <bool RELU>
__global__ __launch_bounds__(TPB) void k_agg64(const float* __restrict__ H,
                                               const int* __restrict__ ebuf,
                                               const int* __restrict__ start,
                                               const unsigned int* __restrict__ deg,
                                               const float* __restrict__ dinv,
                                               const float* __restrict__ b,
                                               float* __restrict__ Out, int n) {
    int node = (blockIdx.x * TPB + threadIdx.x) >> 6;  // wave per node
    int lane = threadIdx.x & 63;
    if (node >= n) return;
    float s = H[(size_t)node * 64 + lane];             // self loop term
    int st = start[node];
    int cnt = (int)deg[node];
    int sn = (cnt > 0) ? ebuf[st] : 0;
    for (int t = 0; t < cnt; ++t) {
        int cur = sn;
        if (t + 1 < cnt) sn = ebuf[st + t + 1];        // prefetch next src idx
        s += H[(size_t)cur * 64 + lane];
    }
    float v = dinv[node] * s + b[lane];
    if (RELU) v = fmaxf(v, 0.f);
    Out[(size_t)node * 64 + lane] = v;
}

// F=16 variant: 4 nodes per wave (16 lanes each), no relu (final layer)
__global__ __launch_bounds__(TPB) void k_agg16(const float* __restrict__ H,
                                               const int* __restrict__ ebuf,
                                               const int* __restrict__ start,
                                               const unsigned int* __restrict__ deg,
                                               const float* __restrict__ dinv,
                                               const float* __restrict__ b,
                                               float* __restrict__ Out, int n) {
    int tid = blockIdx.x * TPB + threadIdx.x;
    int node = tid >> 4;
    int feat = tid & 15;
    if (node >= n) return;
    float s = H[(size_t)node * 16 + feat];
    int st = start[node];
    int cnt = (int)deg[node];
    for (int t = 0; t < cnt; ++t) {
        int cur = ebuf[st + t];
        s += H[(size_t)cur * 16 + feat];
    }
    Out[(size_t)node * 16 + feat] = dinv[node] * s + b[feat];
}

static inline size_t align256(size_t x) { return (x + 255) & ~(size_t)255; }

extern "C" void kernel_launch(void* const* d_in, const int* in_sizes, int n_in,
                              void* d_out, int out_size, void* d_ws, size_t ws_size,
                              hipStream_t stream) {
    const float* x  = (const float*)d_in[0];
    const int* ei   = (const int*)d_in[1];
    const float* W1 = (const float*)d_in[2];
    const float* b1 = (const float*)d_in[3];
    const float* W2 = (const float*)d_in[4];
    const float* b2 = (const float*)d_in[5];
    const float* W3 = (const float*)d_in[6];
    const float* b3 = (const float*)d_in[7];
    const float* W4 = (const float*)d_in[8];
    const float* b4 = (const float*)d_in[9];
    float* out = (float*)d_out;

    const int N = in_sizes[0] / 128;
    const int E = in_sizes[1] / 2;
    const int* src = ei;
    const int* dst = ei + E;

    // workspace layout
    char* p = (char*)d_ws;
    size_t off = 0;
    unsigned int* deg = (unsigned int*)(p + off); off += align256((size_t)N * 4);
    unsigned int* cursor = (unsigned int*)(p + off); off += align256((size_t)N * 4);
    unsigned int* gcounter = (unsigned int*)(p + off); off += 256;
    size_t zero_bytes = off;                       // deg + cursor + gcounter
    int* start = (int*)(p + off); off += align256((size_t)N * 4);
    float* dinv = (float*)(p + off); off += align256((size_t)N * 4);
    int* ebuf = (int*)(p + off); off += align256((size_t)E * 4);
    float* hA = (float*)(p + off); off += align256((size_t)N * 64 * 4);
    float* hB = (float*)(p + off); off += align256((size_t)N * 64 * 4);
    (void)ws_size;

    hipMemsetAsync(d_ws, 0, zero_bytes, stream);

    int gE = (E + TPB - 1) / TPB;
    int gN = (N + TPB - 1) / TPB;

    k_deg<<<gE, TPB, 0, stream>>>(dst, deg, E);
    k_dinv_start<<<gN, TPB, 0, stream>>>(deg, dinv, start, gcounter, N);
    k_scatter<<<gE, TPB, 0, stream>>>(src, dst, start, cursor, ebuf, E);

    int gAgg64 = (N * 64 + TPB - 1) / TPB;
    int gAgg16 = (N * 16 + TPB - 1) / TPB;

    // layer 1: 128 -> 64
    k_gemm<128, 64><<<gN, TPB, 0, stream>>>(x, W1, dinv, hA, N);
    k_agg64<true><<<gAgg64, TPB, 0, stream>>>(hA, ebuf, start, deg, dinv, b1, hB, N);
    // layer 2: 64 -> 64
    k_gemm<64, 64><<<gN, TPB, 0, stream>>>(hB, W2, dinv, hA, N);
    k_agg64<true><<<gAgg64, TPB, 0, stream>>>(hA, ebuf, start, deg, dinv, b2, hB, N);
    // layer 3: 64 -> 64
    k_gemm<64, 64><<<gN, TPB, 0, stream>>>(hB, W3, dinv, hA, N);
    k_agg64<true><<<gAgg64, TPB, 0, stream>>>(hA, ebuf, start, deg, dinv, b3, hB, N);
    // layer 4: 64 -> 16, no relu
    k_gemm<64, 16><<<gN, TPB, 0, stream>>>(hB, W4, dinv, hA, N);
    k_agg16<<<gAgg16, TPB, 0, stream>>>(hA, ebuf, start, deg, dinv, b4, out, N);
}

// Round 2
// 508.095 us; speedup vs baseline: 1.3528x; 1.3528x over previous
//
#include <hip/hip_runtime.h>
#include <hip/hip_bf16.h>
#include <stdint.h>

// GCN 4-layer: h = relu(D^-1/2 (A+I) D^-1/2 (x W) + b) x3, final layer no relu.
// Strategy: fold dinv into GEMM output (h' = xW * dinv[row]); build CSR-ish
// edge partition per call; aggregation = gather + sum, wave-per-node, with
// 8-deep unrolled gathers for memory-level parallelism (R1: latency-bound).

#define TPB 256

__global__ __launch_bounds__(TPB) void k_deg(const int* __restrict__ dst,
                                             unsigned int* __restrict__ deg, int E) {
    int e = blockIdx.x * TPB + threadIdx.x;
    if (e < E) atomicAdd(&deg[dst[e]], 1u);
}

__global__ __launch_bounds__(TPB) void k_dinv_start(const unsigned int* __restrict__ deg,
                                                    float* __restrict__ dinv,
                                                    int* __restrict__ start,
                                                    unsigned int* __restrict__ gcounter,
                                                    int n) {
    int i = blockIdx.x * TPB + threadIdx.x;
    int lane = threadIdx.x & 63;
    int d = 0;
    if (i < n) {
        unsigned int dg = deg[i];
        d = (int)dg;
        dinv[i] = rsqrtf((float)(dg + 1u));   // +1 self loop; always > 0
    }
    // wave-inclusive scan of d
    int v = d;
#pragma unroll
    for (int off = 1; off < 64; off <<= 1) {
        int u = __shfl_up(v, off, 64);
        if (lane >= off) v += u;
    }
    int total = __shfl(v, 63, 64);
    int base = 0;
    if (lane == 0) base = (int)atomicAdd(gcounter, (unsigned int)total);
    base = __shfl(base, 0, 64);
    if (i < n) start[i] = base + v - d;       // exclusive within wave + global base
}

__global__ __launch_bounds__(TPB) void k_scatter(const int* __restrict__ src,
                                                 const int* __restrict__ dst,
                                                 const int* __restrict__ start,
                                                 unsigned int* __restrict__ cursor,
                                                 int* __restrict__ ebuf, int E) {
    int e = blockIdx.x * TPB + threadIdx.x;
    if (e < E) {
        int d = dst[e];
        unsigned int p = atomicAdd(&cursor[d], 1u);
        ebuf[start[d] + (int)p] = src[e];
    }
}

// H[row, :] = (X[row, :] @ W) * dinv[row]
template <int K, int F>
__global__ __launch_bounds__(TPB) void k_gemm(const float* __restrict__ X,
                                              const float* __restrict__ W,
                                              const float* __restrict__ dinv,
                                              float* __restrict__ H, int n) {
    __shared__ float4 Wl[K * F / 4];
    const float4* W4 = reinterpret_cast<const float4*>(W);
    for (int i = threadIdx.x; i < K * F / 4; i += TPB) Wl[i] = W4[i];
    __syncthreads();
    int row = blockIdx.x * TPB + threadIdx.x;
    if (row >= n) return;
    float4 acc[F / 4];
#pragma unroll
    for (int j = 0; j < F / 4; ++j) acc[j] = float4{0.f, 0.f, 0.f, 0.f};
    const float* xr = X + (size_t)row * K;
#pragma unroll 1
    for (int k = 0; k < K; k += 4) {
        float4 xv = *reinterpret_cast<const float4*>(xr + k);
        float xs[4] = {xv.x, xv.y, xv.z, xv.w};
#pragma unroll
        for (int kk = 0; kk < 4; ++kk) {
            float xk = xs[kk];
#pragma unroll
            for (int j = 0; j < F / 4; ++j) {
                float4 w = Wl[(k + kk) * (F / 4) + j];
                acc[j].x = fmaf(xk, w.x, acc[j].x);
                acc[j].y = fmaf(xk, w.y, acc[j].y);
                acc[j].z = fmaf(xk, w.z, acc[j].z);
                acc[j].w = fmaf(xk, w.w, acc[j].w);
            }
        }
    }
    float di = dinv[row];
    float4* hr = reinterpret_cast<float4*>(H + (size_t)row * F);
#pragma unroll
    for (int j = 0; j < F / 4; ++j) {
        float4 o;
        o.x = acc[j].x * di; o.y = acc[j].y * di;
        o.z = acc[j].z * di; o.w = acc[j].w * di;
        hr[j] = o;
    }
}

// Out[node, lane] = act(dinv[node]*(H[node,lane] + sum_{in-edges} H[src,lane]) + b[lane])
// 8/4/2/1 unrolled gather: batch index loads, then independent row loads -> MLP.
template <bool RELU>
__global__ __launch_bounds__(TPB) void k_agg64(const float* __restrict__ H,
                                               const int* __restrict__ ebuf,
                                               const int* __restrict__ start,
                                               const unsigned int* __restrict__ deg,
                                               const float* __restrict__ dinv,
                                               const float* __restrict__ b,
                                               float* __restrict__ Out, int n) {
    int node = (blockIdx.x * TPB + threadIdx.x) >> 6;  // wave per node
    int lane = threadIdx.x & 63;
    if (node >= n) return;
    float s0 = H[(size_t)node * 64 + lane];            // self loop term
    float s1 = 0.f, s2 = 0.f, s3 = 0.f, s4 = 0.f, s5 = 0.f, s6 = 0.f, s7 = 0.f;
    const int st = start[node];
    const int cnt = (int)deg[node];
    const int* eb = ebuf + st;
    int t = 0;
    for (; t + 8 <= cnt; t += 8) {
        int i0 = eb[t],     i1 = eb[t + 1], i2 = eb[t + 2], i3 = eb[t + 3];
        int i4 = eb[t + 4], i5 = eb[t + 5], i6 = eb[t + 6], i7 = eb[t + 7];
        float v0 = H[(size_t)i0 * 64 + lane];
        float v1 = H[(size_t)i1 * 64 + lane];
        float v2 = H[(size_t)i2 * 64 + lane];
        float v3 = H[(size_t)i3 * 64 + lane];
        float v4 = H[(size_t)i4 * 64 + lane];
        float v5 = H[(size_t)i5 * 64 + lane];
        float v6 = H[(size_t)i6 * 64 + lane];
        float v7 = H[(size_t)i7 * 64 + lane];
        s0 += v0; s1 += v1; s2 += v2; s3 += v3;
        s4 += v4; s5 += v5; s6 += v6; s7 += v7;
    }
    if (t + 4 <= cnt) {
        int i0 = eb[t], i1 = eb[t + 1], i2 = eb[t + 2], i3 = eb[t + 3];
        float v0 = H[(size_t)i0 * 64 + lane];
        float v1 = H[(size_t)i1 * 64 + lane];
        float v2 = H[(size_t)i2 * 64 + lane];
        float v3 = H[(size_t)i3 * 64 + lane];
        s0 += v0; s1 += v1; s2 += v2; s3 += v3;
        t += 4;
    }
    if (t + 2 <= cnt) {
        int i0 = eb[t], i1 = eb[t + 1];
        float v0 = H[(size_t)i0 * 64 + lane];
        float v1 = H[(size_t)i1 * 64 + lane];
        s0 += v0; s1 += v1;
        t += 2;
    }
    if (t < cnt) {
        s0 += H[(size_t)eb[t] * 64 + lane];
    }
    float s = ((s0 + s1) + (s2 + s3)) + ((s4 + s5) + (s6 + s7));
    float v = dinv[node] * s + b[lane];
    if (RELU) v = fmaxf(v, 0.f);
    Out[(size_t)node * 64 + lane] = v;
}

// F=16 variant: 4 nodes per wave (16 lanes each), no relu (final layer)
__global__ __launch_bounds__(TPB) void k_agg16(const float* __restrict__ H,
                                               const int* __restrict__ ebuf,
                                               const int* __restrict__ start,
                                               const unsigned int* __restrict__ deg,
                                               const float* __restrict__ dinv,
                                               const float* __restrict__ b,
                                               float* __restrict__ Out, int n) {
    int tid = blockIdx.x * TPB + threadIdx.x;
    int node = tid >> 4;
    int feat = tid & 15;
    if (node >= n) return;
    float s0 = H[(size_t)node * 16 + feat];
    float s1 = 0.f, s2 = 0.f, s3 = 0.f, s4 = 0.f, s5 = 0.f, s6 = 0.f, s7 = 0.f;
    const int st = start[node];
    const int cnt = (int)deg[node];
    const int* eb = ebuf + st;
    int t = 0;
    for (; t + 8 <= cnt; t += 8) {
        int i0 = eb[t],     i1 = eb[t + 1], i2 = eb[t + 2], i3 = eb[t + 3];
        int i4 = eb[t + 4], i5 = eb[t + 5], i6 = eb[t + 6], i7 = eb[t + 7];
        float v0 = H[(size_t)i0 * 16 + feat];
        float v1 = H[(size_t)i1 * 16 + feat];
        float v2 = H[(size_t)i2 * 16 + feat];
        float v3 = H[(size_t)i3 * 16 + feat];
        float v4 = H[(size_t)i4 * 16 + feat];
        float v5 = H[(size_t)i5 * 16 + feat];
        float v6 = H[(size_t)i6 * 16 + feat];
        float v7 = H[(size_t)i7 * 16 + feat];
        s0 += v0; s1 += v1; s2 += v2; s3 += v3;
        s4 += v4; s5 += v5; s6 += v6; s7 += v7;
    }
    if (t + 4 <= cnt) {
        int i0 = eb[t], i1 = eb[t + 1], i2 = eb[t + 2], i3 = eb[t + 3];
        float v0 = H[(size_t)i0 * 16 + feat];
        float v1 = H[(size_t)i1 * 16 + feat];
        float v2 = H[(size_t)i2 * 16 + feat];
        float v3 = H[(size_t)i3 * 16 + feat];
        s0 += v0; s1 += v1; s2 += v2; s3 += v3;
        t += 4;
    }
    if (t + 2 <= cnt) {
        int i0 = eb[t], i1 = eb[t + 1];
        float v0 = H[(size_t)i0 * 16 + feat];
        float v1 = H[(size_t)i1 * 16 + feat];
        s0 += v0; s1 += v1;
        t += 2;
    }
    if (t < cnt) {
        s0 += H[(size_t)eb[t] * 16 + feat];
    }
    float s = ((s0 + s1) + (s2 + s3)) + ((s4 + s5) + (s6 + s7));
    Out[(size_t)node * 16 + feat] = dinv[node] * s + b[feat];
}

static inline size_t align256(size_t x) { return (x + 255) & ~(size_t)255; }

extern "C" void kernel_launch(void* const* d_in, const int* in_sizes, int n_in,
                              void* d_out, int out_size, void* d_ws, size_t ws_size,
                              hipStream_t stream) {
    const float* x  = (const float*)d_in[0];
    const int* ei   = (const int*)d_in[1];
    const float* W1 = (const float*)d_in[2];
    const float* b1 = (const float*)d_in[3];
    const float* W2 = (const float*)d_in[4];
    const float* b2 = (const float*)d_in[5];
    const float* W3 = (const float*)d_in[6];
    const float* b3 = (const float*)d_in[7];
    const float* W4 = (const float*)d_in[8];
    const float* b4 = (const float*)d_in[9];
    float* out = (float*)d_out;

    const int N = in_sizes[0] / 128;
    const int E = in_sizes[1] / 2;
    const int* src = ei;
    const int* dst = ei + E;

    // workspace layout
    char* p = (char*)d_ws;
    size_t off = 0;
    unsigned int* deg = (unsigned int*)(p + off); off += align256((size_t)N * 4);
    unsigned int* cursor = (unsigned int*)(p + off); off += align256((size_t)N * 4);
    unsigned int* gcounter = (unsigned int*)(p + off); off += 256;
    size_t zero_bytes = off;                       // deg + cursor + gcounter
    int* start = (int*)(p + off); off += align256((size_t)N * 4);
    float* dinv = (float*)(p + off); off += align256((size_t)N * 4);
    int* ebuf = (int*)(p + off); off += align256((size_t)E * 4);
    float* hA = (float*)(p + off); off += align256((size_t)N * 64 * 4);
    float* hB = (float*)(p + off); off += align256((size_t)N * 64 * 4);
    (void)ws_size;

    hipMemsetAsync(d_ws, 0, zero_bytes, stream);

    int gE = (E + TPB - 1) / TPB;
    int gN = (N + TPB - 1) / TPB;

    k_deg<<<gE, TPB, 0, stream>>>(dst, deg, E);
    k_dinv_start<<<gN, TPB, 0, stream>>>(deg, dinv, start, gcounter, N);
    k_scatter<<<gE, TPB, 0, stream>>>(src, dst, start, cursor, ebuf, E);

    int gAgg64 = (N * 64 + TPB - 1) / TPB;
    int gAgg16 = (N * 16 + TPB - 1) / TPB;

    // layer 1: 128 -> 64
    k_gemm<128, 64><<<gN, TPB, 0, stream>>>(x, W1, dinv, hA, N);
    k_agg64<true><<<gAgg64, TPB, 0, stream>>>(hA, ebuf, start, deg, dinv, b1, hB, N);
    // layer 2: 64 -> 64
    k_gemm<64, 64><<<gN, TPB, 0, stream>>>(hB, W2, dinv, hA, N);
    k_agg64<true><<<gAgg64, TPB, 0, stream>>>(hA, ebuf, start, deg, dinv, b2, hB, N);
    // layer 3: 64 -> 64
    k_gemm<64, 64><<<gN, TPB, 0, stream>>>(hB, W3, dinv, hA, N);
    k_agg64<true><<<gAgg64, TPB, 0, stream>>>(hA, ebuf, start, deg, dinv, b3, hB, N);
    // layer 4: 64 -> 16, no relu
    k_gemm<64, 16><<<gN, TPB, 0, stream>>>(hB, W4, dinv, hA, N);
    k_agg16<<<gAgg16, TPB, 0, stream>>>(hA, ebuf, start, deg, dinv, b4, out, N);
}

// Round 3
// 504.886 us; speedup vs baseline: 1.3614x; 1.0064x over previous
//
#include <hip/hip_runtime.h>
#include <hip/hip_bf16.h>
#include <stdint.h>

// GCN 4-layer. R3: (a) scatter: cursor pre-init to start + 4-edge MLP;
// (b) GEMMs via wave-per-node, W-column-in-VGPR + v_readlane broadcast (no LDS);
// (c) fuse aggregation with next layer's GEMM (3 fused kernels).

#define TPB 256

__device__ __forceinline__ float bcast(float v, int k) {
    return __int_as_float(__builtin_amdgcn_readlane(__float_as_int(v), k));
}

__global__ __launch_bounds__(TPB) void k_deg(const int* __restrict__ dst,
                                             unsigned int* __restrict__ deg, int E) {
    int i = blockIdx.x * TPB + threadIdx.x;
    int stride = gridDim.x * TPB;
    int e0 = i, e1 = i + stride, e2 = i + 2 * stride, e3 = i + 3 * stride;
    int d0 = (e0 < E) ? dst[e0] : -1;
    int d1 = (e1 < E) ? dst[e1] : -1;
    int d2 = (e2 < E) ? dst[e2] : -1;
    int d3 = (e3 < E) ? dst[e3] : -1;
    if (d0 >= 0) atomicAdd(&deg[d0], 1u);
    if (d1 >= 0) atomicAdd(&deg[d1], 1u);
    if (d2 >= 0) atomicAdd(&deg[d2], 1u);
    if (d3 >= 0) atomicAdd(&deg[d3], 1u);
}

__global__ __launch_bounds__(TPB) void k_dinv_start(const unsigned int* __restrict__ deg,
                                                    float* __restrict__ dinv,
                                                    int* __restrict__ start,
                                                    int* __restrict__ cursor,
                                                    unsigned int* __restrict__ gcounter,
                                                    int n) {
    int i = blockIdx.x * TPB + threadIdx.x;
    int lane = threadIdx.x & 63;
    int d = 0;
    if (i < n) {
        unsigned int dg = deg[i];
        d = (int)dg;
        dinv[i] = rsqrtf((float)(dg + 1u));   // +1 self loop; always > 0
    }
    int v = d;
#pragma unroll
    for (int off = 1; off < 64; off <<= 1) {
        int u = __shfl_up(v, off, 64);
        if (lane >= off) v += u;
    }
    int total = __shfl(v, 63, 64);
    int base = 0;
    if (lane == 0) base = (int)atomicAdd(gcounter, (unsigned int)total);
    base = __shfl(base, 0, 64);
    if (i < n) {
        int s = base + v - d;
        start[i] = s;
        cursor[i] = s;      // scatter appends directly from start
    }
}

__global__ __launch_bounds__(TPB) void k_scatter(const int* __restrict__ src,
                                                 const int* __restrict__ dst,
                                                 int* __restrict__ cursor,
                                                 int* __restrict__ ebuf, int E) {
    int i = blockIdx.x * TPB + threadIdx.x;
    int stride = gridDim.x * TPB;
    int e0 = i, e1 = i + stride, e2 = i + 2 * stride, e3 = i + 3 * stride;
    int d0 = -1, d1 = -1, d2 = -1, d3 = -1;
    int s0 = 0, s1 = 0, s2 = 0, s3 = 0;
    if (e0 < E) { d0 = dst[e0]; s0 = src[e0]; }
    if (e1 < E) { d1 = dst[e1]; s1 = src[e1]; }
    if (e2 < E) { d2 = dst[e2]; s2 = src[e2]; }
    if (e3 < E) { d3 = dst[e3]; s3 = src[e3]; }
    int p0 = (d0 >= 0) ? atomicAdd(&cursor[d0], 1) : 0;
    int p1 = (d1 >= 0) ? atomicAdd(&cursor[d1], 1) : 0;
    int p2 = (d2 >= 0) ? atomicAdd(&cursor[d2], 1) : 0;
    int p3 = (d3 >= 0) ? atomicAdd(&cursor[d3], 1) : 0;
    if (d0 >= 0) ebuf[p0] = s0;
    if (d1 >= 0) ebuf[p1] = s1;
    if (d2 >= 0) ebuf[p2] = s2;
    if (d3 >= 0) ebuf[p3] = s3;
}

// Layer-1 GEMM: H[node,lane] = (X[node,:] @ W)[lane] * dinv[node]; K=128.
// Wave per node, W column `lane` in VGPRs, x broadcast via readlane.
__global__ __launch_bounds__(TPB, 3) void k_gemm_rl128(const float* __restrict__ X,
                                                       const float* __restrict__ W,
                                                       const float* __restrict__ dinv,
                                                       float* __restrict__ H,
                                                       int n, int nwaves) {
    int lane = threadIdx.x & 63;
    int wid = blockIdx.x * (TPB / 64) + (threadIdx.x >> 6);
    float w[128];
#pragma unroll
    for (int k = 0; k < 128; ++k) w[k] = W[k * 64 + lane];
    for (int node = wid; node < n; node += nwaves) {
        const float* xr = X + (size_t)node * 128;
        float x0 = xr[lane];
        float x1 = xr[64 + lane];
        float a0 = 0.f, a1 = 0.f, a2 = 0.f, a3 = 0.f;
#pragma unroll
        for (int k = 0; k < 64; k += 4) {
            a0 = fmaf(bcast(x0, k + 0), w[k + 0], a0);
            a1 = fmaf(bcast(x0, k + 1), w[k + 1], a1);
            a2 = fmaf(bcast(x0, k + 2), w[k + 2], a2);
            a3 = fmaf(bcast(x0, k + 3), w[k + 3], a3);
        }
#pragma unroll
        for (int k = 0; k < 64; k += 4) {
            a0 = fmaf(bcast(x1, k + 0), w[64 + k + 0], a0);
            a1 = fmaf(bcast(x1, k + 1), w[64 + k + 1], a1);
            a2 = fmaf(bcast(x1, k + 2), w[64 + k + 2], a2);
            a3 = fmaf(bcast(x1, k + 3), w[64 + k + 3], a3);
        }
        H[(size_t)node * 64 + lane] = (((a0 + a1) + (a2 + a3))) * dinv[node];
    }
}

// Fused: v = relu(dinv[node]*(H[node]+sum_nbrs H[src]) + b); Hout = (v @ W)*dinv.
// FOUT = 64 (layers 2,3) or 16 (layer 4's GEMM).
template <int FOUT>
__global__ __launch_bounds__(TPB, 3) void k_agg_gemm(const float* __restrict__ H,
                                                     const int* __restrict__ ebuf,
                                                     const int* __restrict__ start,
                                                     const unsigned int* __restrict__ deg,
                                                     const float* __restrict__ dinv,
                                                     const float* __restrict__ b,
                                                     const float* __restrict__ W,
                                                     float* __restrict__ Hout,
                                                     int n, int nwaves) {
    int lane = threadIdx.x & 63;
    int wid = blockIdx.x * (TPB / 64) + (threadIdx.x >> 6);
    int col = (FOUT == 64) ? lane : (lane & (FOUT - 1));
    float w[64];
#pragma unroll
    for (int k = 0; k < 64; ++k) w[k] = W[k * FOUT + col];
    float bl = b[lane];
    for (int node = wid; node < n; node += nwaves) {
        float s0 = H[(size_t)node * 64 + lane];          // self loop
        float s1 = 0.f, s2 = 0.f, s3 = 0.f, s4 = 0.f, s5 = 0.f, s6 = 0.f, s7 = 0.f;
        const int st = start[node];
        const int cnt = (int)deg[node];
        const int* eb = ebuf + st;
        int t = 0;
        for (; t + 8 <= cnt; t += 8) {
            int i0 = eb[t],     i1 = eb[t + 1], i2 = eb[t + 2], i3 = eb[t + 3];
            int i4 = eb[t + 4], i5 = eb[t + 5], i6 = eb[t + 6], i7 = eb[t + 7];
            float v0 = H[(size_t)i0 * 64 + lane];
            float v1 = H[(size_t)i1 * 64 + lane];
            float v2 = H[(size_t)i2 * 64 + lane];
            float v3 = H[(size_t)i3 * 64 + lane];
            float v4 = H[(size_t)i4 * 64 + lane];
            float v5 = H[(size_t)i5 * 64 + lane];
            float v6 = H[(size_t)i6 * 64 + lane];
            float v7 = H[(size_t)i7 * 64 + lane];
            s0 += v0; s1 += v1; s2 += v2; s3 += v3;
            s4 += v4; s5 += v5; s6 += v6; s7 += v7;
        }
        if (t + 4 <= cnt) {
            int i0 = eb[t], i1 = eb[t + 1], i2 = eb[t + 2], i3 = eb[t + 3];
            float v0 = H[(size_t)i0 * 64 + lane];
            float v1 = H[(size_t)i1 * 64 + lane];
            float v2 = H[(size_t)i2 * 64 + lane];
            float v3 = H[(size_t)i3 * 64 + lane];
            s0 += v0; s1 += v1; s2 += v2; s3 += v3;
            t += 4;
        }
        if (t + 2 <= cnt) {
            int i0 = eb[t], i1 = eb[t + 1];
            float v0 = H[(size_t)i0 * 64 + lane];
            float v1 = H[(size_t)i1 * 64 + lane];
            s0 += v0; s1 += v1;
            t += 2;
        }
        if (t < cnt) s0 += H[(size_t)eb[t] * 64 + lane];
        float di = dinv[node];
        float s = ((s0 + s1) + (s2 + s3)) + ((s4 + s5) + (s6 + s7));
        float v = fmaf(di, s, bl);
        v = fmaxf(v, 0.f);                                // relu (layer output)
        float a0 = 0.f, a1 = 0.f, a2 = 0.f, a3 = 0.f;
#pragma unroll
        for (int k = 0; k < 64; k += 4) {
            a0 = fmaf(bcast(v, k + 0), w[k + 0], a0);
            a1 = fmaf(bcast(v, k + 1), w[k + 1], a1);
            a2 = fmaf(bcast(v, k + 2), w[k + 2], a2);
            a3 = fmaf(bcast(v, k + 3), w[k + 3], a3);
        }
        float o = (((a0 + a1) + (a2 + a3))) * di;
        if (FOUT == 64) {
            Hout[(size_t)node * 64 + lane] = o;
        } else if (lane < FOUT) {
            Hout[(size_t)node * FOUT + lane] = o;
        }
    }
}

// Final aggregation on F=16 rows: 4 nodes per wave, no relu.
__global__ __launch_bounds__(TPB) void k_agg16(const float* __restrict__ H,
                                               const int* __restrict__ ebuf,
                                               const int* __restrict__ start,
                                               const unsigned int* __restrict__ deg,
                                               const float* __restrict__ dinv,
                                               const float* __restrict__ b,
                                               float* __restrict__ Out, int n) {
    int tid = blockIdx.x * TPB + threadIdx.x;
    int node = tid >> 4;
    int feat = tid & 15;
    if (node >= n) return;
    float s0 = H[(size_t)node * 16 + feat];
    float s1 = 0.f, s2 = 0.f, s3 = 0.f, s4 = 0.f, s5 = 0.f, s6 = 0.f, s7 = 0.f;
    const int st = start[node];
    const int cnt = (int)deg[node];
    const int* eb = ebuf + st;
    int t = 0;
    for (; t + 8 <= cnt; t += 8) {
        int i0 = eb[t],     i1 = eb[t + 1], i2 = eb[t + 2], i3 = eb[t + 3];
        int i4 = eb[t + 4], i5 = eb[t + 5], i6 = eb[t + 6], i7 = eb[t + 7];
        float v0 = H[(size_t)i0 * 16 + feat];
        float v1 = H[(size_t)i1 * 16 + feat];
        float v2 = H[(size_t)i2 * 16 + feat];
        float v3 = H[(size_t)i3 * 16 + feat];
        float v4 = H[(size_t)i4 * 16 + feat];
        float v5 = H[(size_t)i5 * 16 + feat];
        float v6 = H[(size_t)i6 * 16 + feat];
        float v7 = H[(size_t)i7 * 16 + feat];
        s0 += v0; s1 += v1; s2 += v2; s3 += v3;
        s4 += v4; s5 += v5; s6 += v6; s7 += v7;
    }
    if (t + 4 <= cnt) {
        int i0 = eb[t], i1 = eb[t + 1], i2 = eb[t + 2], i3 = eb[t + 3];
        s0 += H[(size_t)i0 * 16 + feat];
        s1 += H[(size_t)i1 * 16 + feat];
        s2 += H[(size_t)i2 * 16 + feat];
        s3 += H[(size_t)i3 * 16 + feat];
        t += 4;
    }
    if (t + 2 <= cnt) {
        int i0 = eb[t], i1 = eb[t + 1];
        s0 += H[(size_t)i0 * 16 + feat];
        s1 += H[(size_t)i1 * 16 + feat];
        t += 2;
    }
    if (t < cnt) s0 += H[(size_t)eb[t] * 16 + feat];
    float s = ((s0 + s1) + (s2 + s3)) + ((s4 + s5) + (s6 + s7));
    Out[(size_t)node * 16 + feat] = dinv[node] * s + b[feat];
}

static inline size_t align256(size_t x) { return (x + 255) & ~(size_t)255; }

extern "C" void kernel_launch(void* const* d_in, const int* in_sizes, int n_in,
                              void* d_out, int out_size, void* d_ws, size_t ws_size,
                              hipStream_t stream) {
    const float* x  = (const float*)d_in[0];
    const int* ei   = (const int*)d_in[1];
    const float* W1 = (const float*)d_in[2];
    const float* b1 = (const float*)d_in[3];
    const float* W2 = (const float*)d_in[4];
    const float* b2 = (const float*)d_in[5];
    const float* W3 = (const float*)d_in[6];
    const float* b3 = (const float*)d_in[7];
    const float* W4 = (const float*)d_in[8];
    const float* b4 = (const float*)d_in[9];
    float* out = (float*)d_out;

    const int N = in_sizes[0] / 128;
    const int E = in_sizes[1] / 2;
    const int* src = ei;
    const int* dst = ei + E;

    // workspace layout: [deg | gcounter] zeroed; rest overwritten each call.
    char* p = (char*)d_ws;
    size_t off = 0;
    unsigned int* deg = (unsigned int*)(p + off); off += align256((size_t)N * 4);
    unsigned int* gcounter = (unsigned int*)(p + off); off += 256;
    size_t zero_bytes = off;
    int* cursor = (int*)(p + off); off += align256((size_t)N * 4);
    int* start = (int*)(p + off); off += align256((size_t)N * 4);
    float* dinv = (float*)(p + off); off += align256((size_t)N * 4);
    int* ebuf = (int*)(p + off); off += align256((size_t)E * 4);
    float* hA = (float*)(p + off); off += align256((size_t)N * 64 * 4);
    float* hB = (float*)(p + off); off += align256((size_t)N * 64 * 4);
    (void)ws_size;

    hipMemsetAsync(d_ws, 0, zero_bytes, stream);

    int gE4 = (E + TPB * 4 - 1) / (TPB * 4);
    int gN = (N + TPB - 1) / TPB;

    k_deg<<<gE4, TPB, 0, stream>>>(dst, deg, E);
    k_dinv_start<<<gN, TPB, 0, stream>>>(deg, dinv, start, cursor, gcounter, N);
    k_scatter<<<gE4, TPB, 0, stream>>>(src, dst, cursor, ebuf, E);

    const int NBLK = 1024;                  // grid-stride wave-per-node kernels
    const int NWAVES = NBLK * (TPB / 64);

    // layer 1 GEMM: x @ W1 * dinv -> hA
    k_gemm_rl128<<<NBLK, TPB, 0, stream>>>(x, W1, dinv, hA, N, NWAVES);
    // agg1 + relu + GEMM W2 -> hB
    k_agg_gemm<64><<<NBLK, TPB, 0, stream>>>(hA, ebuf, start, deg, dinv, b1, W2, hB, N, NWAVES);
    // agg2 + relu + GEMM W3 -> hA
    k_agg_gemm<64><<<NBLK, TPB, 0, stream>>>(hB, ebuf, start, deg, dinv, b2, W3, hA, N, NWAVES);
    // agg3 + relu + GEMM W4 -> hB (N x 16)
    k_agg_gemm<16><<<NBLK, TPB, 0, stream>>>(hA, ebuf, start, deg, dinv, b3, W4, hB, N, NWAVES);
    // final aggregation (no relu)
    int gAgg16 = (N * 16 + TPB - 1) / TPB;
    k_agg16<<<gAgg16, TPB, 0, stream>>>(hB, ebuf, start, deg, dinv, b4, out, N);
}